// Round 1
// 182.749 us; speedup vs baseline: 1.0234x; 1.0234x over previous
//
#include <hip/hip_runtime.h>
#include <math.h>

#define NRES 22

// ---------------- LDS layout (float indices) ----------------
// Tables (block-shared, staged once):
//   sT : rigT 66 records x 100 floats (96 used = 8 frames x 12; pad->100 so
//        b128 record reads spread bank-quartets: (100*rec)%32 = 4*rec.
//        Unpadded 96 would put EVERY record's float4 k on the same quartet.)
//   sG : rigG 66 records x 76 floats (72 used = 24 atoms x 3; pad->76: 19 odd)
//   sTd: tdep 22 x 9 ints  (8 used; odd stride -> conflict-free)
//   sRd: rdep 22 x 25 ints (24 used; odd stride)
// Per-wave dynamic chunk (1856 floats = 7424 B), time-multiplexed:
//   phase 1: staged inputs  o0[64*17] | o1[64*9] | pos[64*3]  (= 1856 floats)
//   phase 2: output transpose, 16 slots x 76 floats (= 1216 floats)
#define ST_F    0
#define SG_F    6600
#define STD_I   11616
#define SRD_I   11814
#define TBL_F   12364      // 49456 B, 16B-aligned
#define CHUNK_F 1856
#define SMEM_BYTES ((TBL_F + 4 * CHUNK_F) * 4)   // 79152 B -> 2 blocks/CU

// Select fr[d] (d in 0..7) into P via a 3-level cndmask tree.
__device__ __forceinline__ void sel8(const float (&fr)[8][12], int d, float (&P)[12]) {
    const bool b0 = (d & 1) != 0;
    const bool b1 = (d & 2) != 0;
    const bool b2 = (d & 4) != 0;
#pragma unroll
    for (int k = 0; k < 12; ++k) {
        float a01 = b0 ? fr[1][k] : fr[0][k];
        float a23 = b0 ? fr[3][k] : fr[2][k];
        float a45 = b0 ? fr[5][k] : fr[4][k];
        float a67 = b0 ? fr[7][k] : fr[6][k];
        float b03 = b1 ? a23 : a01;
        float b47 = b1 ? a67 : a45;
        P[k] = b2 ? b47 : b03;
    }
}

__device__ __forceinline__ void apply_point(const float (&F)[12], float x, float y, float z,
                                            float &px, float &py, float &pz) {
    px = fmaf(F[0], x, fmaf(F[1], y, fmaf(F[2], z, F[9])));
    py = fmaf(F[3], x, fmaf(F[4], y, fmaf(F[5], z, F[10])));
    pz = fmaf(F[6], x, fmaf(F[7], y, fmaf(F[8], z, F[11])));
}

// Wave-local coalesced global->LDS staging (src 16B-aligned at wave granularity).
__device__ __forceinline__ void wave_stage(const float* __restrict__ src, float* dst,
                                           int nF, int lane) {
    const int n4 = nF >> 2;
    const float4* s4 = (const float4*)src;
    float4* d4 = (float4*)dst;
    for (int i = lane; i < n4; i += 64) d4[i] = s4[i];
    const int rem = nF & 3;
    if (lane < rem) {
        const int b = n4 << 2;
        dst[b + lane] = src[b + lane];
    }
}

extern "C" __global__ __launch_bounds__(256, 2)
void model_kernel(const float* __restrict__ o0,     // (N,17)
                  const float* __restrict__ o1,     // (N,3,3)
                  const float* __restrict__ pos,    // (N,3)
                  const int*   __restrict__ ssArr,  // (N,)
                  const int*   __restrict__ rtArr,  // (N,)
                  const float* __restrict__ rigT,   // (3,22,8,4,3)
                  const float* __restrict__ rigG,   // (3,22,24,3)
                  const int*   __restrict__ tdepArr,// (22,8)
                  const int*   __restrict__ rdepArr,// (22,24)
                  float* __restrict__ outR,         // (N,24,3)
                  float* __restrict__ outF,         // (N,4,3)
                  int N)
{
    extern __shared__ __align__(16) float smem[];
    int* smemI = (int*)smem;
    const int tid  = threadIdx.x;
    const int lane = tid & 63;
    const int wave = tid >> 6;

    // ---- stage tables into LDS (coalesced global reads, padded LDS writes) ----
    {
        const float4* s4 = (const float4*)rigT;        // 6336 floats = 1584 float4
        for (int t = tid; t < 1584; t += 256) {
            float4 v = s4[t];
            int rec = t / 24;                           // (4t)/96
            int k   = (t - rec * 24) << 2;              // multiple of 4 -> b128 aligned
            *(float4*)(smem + ST_F + rec * 100 + k) = v;
        }
    }
    {
        const float4* s4 = (const float4*)rigG;        // 4752 floats = 1188 float4
        for (int t = tid; t < 1188; t += 256) {
            float4 v = s4[t];
            int rec = t / 18;                           // (4t)/72
            int k   = (t - rec * 18) << 2;
            *(float4*)(smem + SG_F + rec * 76 + k) = v;
        }
    }
    for (int t = tid; t < 176; t += 256)
        smemI[STD_I + (t >> 3) * 9 + (t & 7)] = tdepArr[t];
    for (int t = tid; t < 528; t += 256) {
        int r = t / 24;
        smemI[SRD_I + r * 25 + (t - r * 24)] = rdepArr[t];
    }
    __syncthreads();

    float* chunk = smem + TBL_F + wave * CHUNK_F;
    const int gstride = (int)gridDim.x * 256;

    for (int base = (int)blockIdx.x * 256; base < N; base += gstride) {
        const int wres0 = base + wave * 64;
        const int cnt   = min(64, N - wres0);           // may be <= 0

        // WAR fence vs previous iteration's chunk reads (wave-local reuse)
        asm volatile("s_waitcnt lgkmcnt(0)" ::: "memory");

        if (cnt > 0) {
            wave_stage(o0  + (size_t)wres0 * 17, chunk,        cnt * 17, lane);
            wave_stage(o1  + (size_t)wres0 * 9,  chunk + 1088, cnt * 9,  lane);
            wave_stage(pos + (size_t)wres0 * 3,  chunk + 1664, cnt * 3,  lane);
        }
        asm volatile("s_waitcnt lgkmcnt(0)" ::: "memory");

        const int  res   = wres0 + lane;
        const bool alive = (lane < cnt);

        float  fr[8][12];
        float4 out4[18];

        if (alive) {
            const int s    = ssArr[res];
            const int rt   = rtArr[res];
            const int sr22 = s * NRES + rt;

            // ---- torsion cos/sin (normalize pairs) from LDS (stride 17 = odd) ----
            const float* myo0 = chunk + lane * 17;
            float c[7], sn[7];
#pragma unroll
            for (int t = 0; t < 7; ++t) {
                float cr = myo0[2 * t], sr = myo0[2 * t + 1];
                float inv = rsqrtf(fmaxf(cr * cr + sr * sr, 1e-12f));
                c[t]  = cr * inv;
                sn[t] = sr * inv;
            }

            // ---- backbone frame (Gram-Schmidt) ----
            const float* myo1 = chunk + 1088 + lane * 9;
            float r0x = myo1[0], r0y = myo1[1], r0z = myo1[2];
            float v1x = myo1[3], v1y = myo1[4], v1z = myo1[5];
            float t2x = myo1[6], t2y = myo1[7], t2z = myo1[8];
            float inv0 = rsqrtf(fmaxf(r0x * r0x + r0y * r0y + r0z * r0z, 1e-12f));
            float e0x = r0x * inv0, e0y = r0y * inv0, e0z = r0z * inv0;
            float d01 = e0x * v1x + e0y * v1y + e0z * v1z;
            float u1x = v1x - e0x * d01, u1y = v1y - e0y * d01, u1z = v1z - e0z * d01;
            float inv1 = rsqrtf(fmaxf(u1x * u1x + u1y * u1y + u1z * u1z, 1e-12f));
            float e1x = u1x * inv1, e1y = u1y * inv1, e1z = u1z * inv1;
            float e2x = e0y * e1z - e0z * e1y;
            float e2y = e0z * e1x - e0x * e1z;
            float e2z = e0x * e1y - e0y * e1x;
            const float* myp = chunk + 1664 + lane * 3;
            float btx = 0.1f * t2x + myp[0];
            float bty = 0.1f * t2y + myp[1];
            float btz = 0.1f * t2z + myp[2];

            // ---- frames from LDS rigT (record = sr22*100 floats = sr22*25 float4) ----
            const float4* T4 = (const float4*)smem + sr22 * 25;

            // frame 0 = combine(T0, [rot(cols e0,e1,e2); bt])
            {
                float4 q0 = T4[0], q1 = T4[1], q2 = T4[2];
                float T0[12] = {q0.x, q0.y, q0.z, q0.w, q1.x, q1.y, q1.z, q1.w,
                                q2.x, q2.y, q2.z, q2.w};
#pragma unroll
                for (int i = 0; i < 3; ++i) {
                    float a = T0[i * 3 + 0], b = T0[i * 3 + 1], d = T0[i * 3 + 2];
                    fr[0][i * 3 + 0] = a * e0x + b * e0y + d * e0z;
                    fr[0][i * 3 + 1] = a * e1x + b * e1y + d * e1z;
                    fr[0][i * 3 + 2] = a * e2x + b * e2y + d * e2z;
                    fr[0][9 + i]     = a * btx + b * bty + d * btz + T0[9 + i];
                }
            }

            // frames 1..7 = combine(Tf, rotX(c,s))
#pragma unroll
            for (int f = 1; f < 8; ++f) {
                float4 q0 = T4[f * 3 + 0], q1 = T4[f * 3 + 1], q2 = T4[f * 3 + 2];
                float Tf[12] = {q0.x, q0.y, q0.z, q0.w, q1.x, q1.y, q1.z, q1.w,
                                q2.x, q2.y, q2.z, q2.w};
                float cc = c[f - 1], ssn = sn[f - 1];
#pragma unroll
                for (int i = 0; i < 3; ++i) {
                    fr[f][i * 3 + 0] = Tf[i * 3 + 0];
                    fr[f][i * 3 + 1] = Tf[i * 3 + 1] * cc + Tf[i * 3 + 2] * ssn;
                    fr[f][i * 3 + 2] = Tf[i * 3 + 2] * cc - Tf[i * 3 + 1] * ssn;
                    fr[f][9 + i]     = Tf[9 + i];
                }
            }

            // ---- sequential dependency chain (tdep from LDS, stride 9 = odd) ----
            const int* tdp = smemI + STD_I + rt * 9;
#pragma unroll
            for (int i = 1; i < 8; ++i) {
                float P[12];
                sel8(fr, tdp[i] & 7, P);
                float Y[12];
#pragma unroll
                for (int k = 0; k < 12; ++k) Y[k] = fr[i][k];
#pragma unroll
                for (int r = 0; r < 3; ++r) {
                    float a = P[r * 3 + 0], b = P[r * 3 + 1], d = P[r * 3 + 2];
#pragma unroll
                    for (int j = 0; j < 3; ++j)
                        fr[i][r * 3 + j] = a * Y[j] + b * Y[3 + j] + d * Y[6 + j];
                    fr[i][9 + r] = a * Y[9] + b * Y[10] + d * Y[11] + P[9 + r];
                }
            }

            // ---- second output: opr[:,0] (48B stride, aligned float4, direct) ----
            float4* OF4 = (float4*)outF + (size_t)res * 3;
            OF4[0] = make_float4(fr[0][0], fr[0][1], fr[0][2], fr[0][3]);
            OF4[1] = make_float4(fr[0][4], fr[0][5], fr[0][6], fr[0][7]);
            OF4[2] = make_float4(fr[0][8], fr[0][9], fr[0][10], fr[0][11]);

            // ---- atoms: 24 point transforms, rigG/rdep from LDS, buffer in regs ----
            const float4* G4  = (const float4*)smem + 1650 + sr22 * 19;  // SG_F/4 + rec*76/4
            const int*    rdp = smemI + SRD_I + rt * 25;
#pragma unroll
            for (int ck = 0; ck < 6; ++ck) {
                int d0 = rdp[ck * 4 + 0] & 7, d1 = rdp[ck * 4 + 1] & 7;
                int d2 = rdp[ck * 4 + 2] & 7, d3 = rdp[ck * 4 + 3] & 7;
                float4 g0 = G4[ck * 3 + 0], g1 = G4[ck * 3 + 1], g2 = G4[ck * 3 + 2];
                float P[12];
                float p0x, p0y, p0z, p1x, p1y, p1z, p2x, p2y, p2z, p3x, p3y, p3z;
                sel8(fr, d0, P); apply_point(P, g0.x, g0.y, g0.z, p0x, p0y, p0z);
                sel8(fr, d1, P); apply_point(P, g0.w, g1.x, g1.y, p1x, p1y, p1z);
                sel8(fr, d2, P); apply_point(P, g1.z, g1.w, g2.x, p2x, p2y, p2z);
                sel8(fr, d3, P); apply_point(P, g2.y, g2.z, g2.w, p3x, p3y, p3z);
                out4[ck * 3 + 0] = make_float4(p0x, p0y, p0z, p1x);
                out4[ck * 3 + 1] = make_float4(p1y, p1z, p2x, p2y);
                out4[ck * 3 + 2] = make_float4(p2z, p3x, p3y, p3z);
            }
        }

        // ---- outR: quarter-wave LDS transpose -> coalesced float4 stores ----
        // Round r: 16 residues (lanes 16r..16r+15) dump 72 floats into padded
        // slots (stride 76 floats: quartet = 19*slot+j mod 8 -> 2-way, free),
        // then all 64 lanes store the 4.5KB globally-contiguous range.
#pragma unroll 1
        for (int r = 0; r < 4; ++r) {
            const int rb = wres0 + r * 16;
            const int vr = min(16, N - rb);
            if (vr > 0) {
                asm volatile("s_waitcnt lgkmcnt(0)" ::: "memory"); // WAR vs prev round reads
                if ((lane >> 4) == r && (lane & 15) < vr) {
                    float4* slotp = (float4*)(chunk + (lane & 15) * 76);
#pragma unroll
                    for (int j = 0; j < 18; ++j) slotp[j] = out4[j];
                }
                asm volatile("s_waitcnt lgkmcnt(0)" ::: "memory"); // RAW: writes visible
                const float4* c4  = (const float4*)chunk;
                float4*       dst = (float4*)outR + (size_t)rb * 18;
                const int     n4r = vr * 18;
                for (int i = lane; i < n4r; i += 64) {
                    int slot = i / 18;
                    dst[i] = c4[slot * 19 + (i - slot * 18)];
                }
            }
        }
    }
}

extern "C" void kernel_launch(void* const* d_in, const int* in_sizes, int n_in,
                              void* d_out, int out_size, void* d_ws, size_t ws_size,
                              hipStream_t stream) {
    const float* o0   = (const float*)d_in[0];
    const float* o1   = (const float*)d_in[1];
    const float* pos  = (const float*)d_in[2];
    const int*   ssA  = (const int*)d_in[3];
    const int*   rtA  = (const int*)d_in[4];
    const float* rigT = (const float*)d_in[5];
    const float* rigG = (const float*)d_in[6];
    const int*   tdep = (const int*)d_in[7];
    const int*   rdep = (const int*)d_in[8];

    const int N = in_sizes[3]; // ss has N elements
    float* outR = (float*)d_out;
    float* outF = (float*)d_out + (size_t)N * 72;

    static bool attr_set = false;
    if (!attr_set) {
        hipFuncSetAttribute((const void*)model_kernel,
                            hipFuncAttributeMaxDynamicSharedMemorySize, SMEM_BYTES);
        attr_set = true;
    }

    int grid = (N + 255) / 256;
    if (grid > 512) grid = 512;   // persistent: exactly 2 blocks/CU (LDS-bound)
    model_kernel<<<grid, 256, SMEM_BYTES, stream>>>(o0, o1, pos, ssA, rtA, rigT, rigG,
                                                    tdep, rdep, outR, outF, N);
}